// Round 1
// baseline (354.358 us; speedup 1.0000x reference)
//
#include <hip/hip_runtime.h>

#define NN    100000
#define NE    1600000
#define NQ4   (NE / 4)            // 400000 int4/float4 quads
#define D     128
#define NXCD  8
#define NNP   100352              // 98*1024: >= NN, NNP/4 divisible by 256
#define NNP4  (NNP / 4)           // 25088 = 98*256
#define SCATB ((NQ4 + 255) / 256) // 1563 blocks, 1 quad per thread
#define REDB  (NNP4 / 256)        // 98 blocks, 1 float4 per thread

// Per-wave hardware XCD id (verified on MI355X via s_getreg, learn_hip m09).
// Used only to pick a private partial array -> correctness never depends on
// the dispatch->XCD mapping, only L2 locality does.
__device__ __forceinline__ int xcc() {
    int x;
    asm volatile("s_getreg_b32 %0, hwreg(HW_REG_XCC_ID)" : "=s"(x));
    return x & (NXCD - 1);
}

// ---- scatter 1: per-XCD degree partials pDeg[x][v] += w (1 atomic/edge) ----
__global__ __launch_bounds__(256) void k_scat1(const int4* __restrict__ col4,
                                               const float4* __restrict__ w4,
                                               float* __restrict__ pDeg) {
    int e = blockIdx.x * 256 + threadIdx.x;
    if (e >= NQ4) return;
    float* p = pDeg + (size_t)xcc() * NNP;
    int4  c = col4[e];
    float4 w = w4[e];
    atomicAdd(&p[c.x], w.x);
    atomicAdd(&p[c.y], w.y);
    atomicAdd(&p[c.z], w.z);
    atomicAdd(&p[c.w], w.w);
}

// ---- reduce 1: dinv = rsqrt(1 + sum_x pDeg[x][v]); block 0: s1 = colsum(W1), accg = 0 ----
__global__ __launch_bounds__(256) void k_red1(const float* __restrict__ pDeg,
                                              const float* __restrict__ W1,
                                              float* __restrict__ dinv,
                                              float* __restrict__ s1,
                                              float* __restrict__ accg) {
    const int t = threadIdx.x;
    const int v4 = blockIdx.x * 256 + t;       // grid covers NNP4 exactly
    float4 a = make_float4(1.f, 1.f, 1.f, 1.f); // self-loop weight
    #pragma unroll
    for (int x = 0; x < NXCD; ++x) {
        float4 p = ((const float4*)(pDeg + (size_t)x * NNP))[v4];
        a.x += p.x; a.y += p.y; a.z += p.z; a.w += p.w;
    }
    float4 r;
    r.x = rsqrtf(a.x); r.y = rsqrtf(a.y); r.z = rsqrtf(a.z); r.w = rsqrtf(a.w);
    ((float4*)dinv)[v4] = r;

    if (blockIdx.x == 0) {
        __shared__ float tmp[D];
        int j = t & (D - 1), half = t >> 7;    // 2 halves x 64 rows
        float sv = 0.f;
        #pragma unroll 16
        for (int rr = half * 64; rr < half * 64 + 64; ++rr) sv += W1[rr * D + j];
        if (half) tmp[j] = sv;
        __syncthreads();
        if (!half) { s1[j] = sv + tmp[j]; accg[j] = 0.f; }  // ws re-poisoned each call
    }
}

// ---- scatter 2: pS[x][col] += w*dinv[row], pU[x][row] += w*dinv[col] (2 atomics/edge) ----
__global__ __launch_bounds__(256) void k_scat2(const int4* __restrict__ col4,
                                               const int4* __restrict__ row4,
                                               const float4* __restrict__ w4,
                                               const float* __restrict__ dinv,
                                               float* __restrict__ pS,
                                               float* __restrict__ pU) {
    int e = blockIdx.x * 256 + threadIdx.x;
    if (e >= NQ4) return;
    const int x = xcc();
    float* S = pS + (size_t)x * NNP;
    float* U = pU + (size_t)x * NNP;
    int4  c = col4[e];
    int4  r = row4[e];
    float4 w = w4[e];
    // issue all gathers before the atomics (ILP over ~L2 latency)
    float dr0 = dinv[r.x], dr1 = dinv[r.y], dr2 = dinv[r.z], dr3 = dinv[r.w];
    float dc0 = dinv[c.x], dc1 = dinv[c.y], dc2 = dinv[c.z], dc3 = dinv[c.w];
    atomicAdd(&S[c.x], w.x * dr0);
    atomicAdd(&S[c.y], w.y * dr1);
    atomicAdd(&S[c.z], w.z * dr2);
    atomicAdd(&S[c.w], w.w * dr3);
    atomicAdd(&U[r.x], w.x * dc0);
    atomicAdd(&U[r.y], w.y * dc1);
    atomicAdd(&U[r.z], w.z * dc2);
    atomicAdd(&U[r.w], w.w * dc3);
}

// ---- reduce 2 + node-dot (c/wgt never hit HBM):
//  c = dinv*(S+dinv), wgt = dinv*(U+dinv);  accg[j] += sum_v wgt*relu(c*s1[j]+b1[j])
__global__ __launch_bounds__(256) void k_red2node(const float* __restrict__ pS,
                                                  const float* __restrict__ pU,
                                                  const float* __restrict__ dinv,
                                                  const float* __restrict__ s1,
                                                  const float* __restrict__ b1,
                                                  float* __restrict__ accg) {
    __shared__ float4 ldsC[256], ldsW[256];    // 1024 nodes per block
    __shared__ float red[D];
    const int t = threadIdx.x;
    const int v4 = blockIdx.x * 256 + t;       // grid covers NNP4 exactly

    float4 S = make_float4(0, 0, 0, 0), U = make_float4(0, 0, 0, 0);
    #pragma unroll
    for (int x = 0; x < NXCD; ++x) {
        float4 a = ((const float4*)(pS + (size_t)x * NNP))[v4];
        float4 u = ((const float4*)(pU + (size_t)x * NNP))[v4];
        S.x += a.x; S.y += a.y; S.z += a.z; S.w += a.w;
        U.x += u.x; U.y += u.y; U.z += u.z; U.w += u.w;
    }
    float4 dv = ((const float4*)dinv)[v4];
    float4 cc, ww;
    cc.x = dv.x * (S.x + dv.x); cc.y = dv.y * (S.y + dv.y);
    cc.z = dv.z * (S.z + dv.z); cc.w = dv.w * (S.w + dv.w);
    ww.x = dv.x * (U.x + dv.x); ww.y = dv.y * (U.y + dv.y);
    ww.z = dv.z * (U.z + dv.z); ww.w = dv.w * (U.w + dv.w);
    int v0 = v4 * 4;                           // mask padded fake nodes
    if (v0 + 0 >= NN) ww.x = 0.f;
    if (v0 + 1 >= NN) ww.y = 0.f;
    if (v0 + 2 >= NN) ww.z = 0.f;
    if (v0 + 3 >= NN) ww.w = 0.f;
    ldsC[t] = cc; ldsW[t] = ww;
    __syncthreads();

    // node-dot: 2 j-groups of 128 lanes; group g scans 128 float4 node-packs
    const int j = t & (D - 1), g = t >> 7;
    const float sj = s1[j], bj = b1[j];
    float acc = 0.f;
    #pragma unroll 8
    for (int k = 0; k < 128; ++k) {
        float4 c4 = ldsC[g * 128 + k];         // wave-uniform LDS broadcast
        float4 w4 = ldsW[g * 128 + k];
        acc += w4.x * fmaxf(fmaf(c4.x, sj, bj), 0.f);
        acc += w4.y * fmaxf(fmaf(c4.y, sj, bj), 0.f);
        acc += w4.z * fmaxf(fmaf(c4.z, sj, bj), 0.f);
        acc += w4.w * fmaxf(fmaf(c4.w, sj, bj), 0.f);
    }
    if (g) red[j] = acc;
    __syncthreads();
    if (!g) atomicAdd(&accg[j], acc + red[j]); // 128 atomics/block, 98 blocks
}

// ---- gemv: out[k] = (1/N) * sum_j accg[j]*W2[j][k] + b2[k] ----
__global__ __launch_bounds__(256) void k_gemv(const float* __restrict__ accg,
                                              const float* __restrict__ W2,
                                              const float* __restrict__ b2,
                                              float* __restrict__ out) {
    __shared__ float a[D], r2[D];
    int t = threadIdx.x, k = t & (D - 1), g = t >> 7;
    if (t < D) a[t] = accg[t];
    __syncthreads();
    float o = 0.f;
    int j0 = g * 64;
    #pragma unroll 16
    for (int j = j0; j < j0 + 64; ++j) o = fmaf(a[j], W2[j * D + k], o);
    if (g) r2[k] = o;
    __syncthreads();
    if (!g) out[k] = (o + r2[k]) * (1.0f / (float)NN) + b2[k];
}

extern "C" void kernel_launch(void* const* d_in, const int* in_sizes, int n_in,
                              void* d_out, int out_size, void* d_ws, size_t ws_size,
                              hipStream_t stream) {
    // inputs: 0=x (unused; ref overwrites with ones), 1=edge_index [2,E] int,
    //         2=edge_attr [E] f32, 3=W1, 4=b1, 5=W2, 6=b2 (all f32)
    const int* ei    = (const int*)d_in[1];
    const int4* row4 = (const int4*)ei;
    const int4* col4 = (const int4*)(ei + NE);
    const float4* w4 = (const float4*)d_in[2];
    const float* W1 = (const float*)d_in[3];
    const float* b1 = (const float*)d_in[4];
    const float* W2 = (const float*)d_in[5];
    const float* b2 = (const float*)d_in[6];
    float* out = (float*)d_out;

    float* ws   = (float*)d_ws;
    float* pDeg = ws;                          // [NXCD*NNP] degree partials
    float* pS   = pDeg + (size_t)NXCD * NNP;   // [NXCD*NNP]
    float* pU   = pS   + (size_t)NXCD * NNP;   // [NXCD*NNP]
    float* dinv = pU   + (size_t)NXCD * NNP;   // [NNP]
    float* s1   = dinv + NNP;                  // [D]
    float* accg = s1 + D;                      // [D]
    // total ~9.7 MB << ws_size

    hipMemsetAsync(ws, 0, (size_t)3 * NXCD * NNP * sizeof(float), stream);
    k_scat1   <<<SCATB, 256, 0, stream>>>(col4, w4, pDeg);
    k_red1    <<<REDB, 256, 0, stream>>>(pDeg, W1, dinv, s1, accg);
    k_scat2   <<<SCATB, 256, 0, stream>>>(col4, row4, w4, dinv, pS, pU);
    k_red2node<<<REDB, 256, 0, stream>>>(pS, pU, dinv, s1, b1, accg);
    k_gemv    <<<1, 256, 0, stream>>>(accg, W2, b2, out);
}

// Round 2
// 354.228 us; speedup vs baseline: 1.0004x; 1.0004x over previous
//
#include <hip/hip_runtime.h>

#define NN    100000
#define NE    1600000
#define NQ4   (NE / 4)            // 400000 int4/float4 quads
#define D     128
#define NXCD  8
#define NNP   100352              // 98*1024: >= NN, NNP/4 divisible by 256
#define NNP4  (NNP / 4)           // 25088 = 98*256
#define SCATB ((NQ4 + 255) / 256) // 1563 blocks, 1 quad per thread
#define REDB  (NNP4 / 256)        // 98 blocks, 1 float4 per thread

// Per-wave hardware XCD id (verified on MI355X via s_getreg, learn_hip m09).
// Selects a private partial array -> no line is atomically touched by two
// XCDs, so local-L2 hardware atomics are correct; kernel-end release flushes.
__device__ __forceinline__ int xcc() {
    int x;
    asm volatile("s_getreg_b32 %0, hwreg(HW_REG_XCC_ID)" : "=s"(x));
    return x & (NXCD - 1);
}

// Hardware fp32 atomic (global_atomic_add_f32, fire-and-forget, no CAS loop).
// Plain atomicAdd(float*) compiles to a cmpswap retry loop without
// -munsafe-fp-atomics -> 100 MB WRITE_SIZE + latency-bound (round 1 counters).
__device__ __forceinline__ void gadd(float* p, float v) {
    unsafeAtomicAdd(p, v);
}

// ---- scatter 1: per-XCD degree partials pDeg[x][v] += w (1 atomic/edge) ----
__global__ __launch_bounds__(256) void k_scat1(const int4* __restrict__ col4,
                                               const float4* __restrict__ w4,
                                               float* __restrict__ pDeg) {
    int e = blockIdx.x * 256 + threadIdx.x;
    if (e >= NQ4) return;
    float* p = pDeg + (size_t)xcc() * NNP;
    int4  c = col4[e];
    float4 w = w4[e];
    gadd(&p[c.x], w.x);
    gadd(&p[c.y], w.y);
    gadd(&p[c.z], w.z);
    gadd(&p[c.w], w.w);
}

// ---- reduce 1: dinv = rsqrt(1 + sum_x pDeg[x][v]); block 0: s1 = colsum(W1), accg = 0 ----
__global__ __launch_bounds__(256) void k_red1(const float* __restrict__ pDeg,
                                              const float* __restrict__ W1,
                                              float* __restrict__ dinv,
                                              float* __restrict__ s1,
                                              float* __restrict__ accg) {
    const int t = threadIdx.x;
    const int v4 = blockIdx.x * 256 + t;       // grid covers NNP4 exactly
    float4 a = make_float4(1.f, 1.f, 1.f, 1.f); // self-loop weight
    #pragma unroll
    for (int x = 0; x < NXCD; ++x) {
        float4 p = ((const float4*)(pDeg + (size_t)x * NNP))[v4];
        a.x += p.x; a.y += p.y; a.z += p.z; a.w += p.w;
    }
    float4 r;
    r.x = rsqrtf(a.x); r.y = rsqrtf(a.y); r.z = rsqrtf(a.z); r.w = rsqrtf(a.w);
    ((float4*)dinv)[v4] = r;

    if (blockIdx.x == 0) {
        __shared__ float tmp[D];
        int j = t & (D - 1), half = t >> 7;    // 2 halves x 64 rows
        float sv = 0.f;
        #pragma unroll 16
        for (int rr = half * 64; rr < half * 64 + 64; ++rr) sv += W1[rr * D + j];
        if (half) tmp[j] = sv;
        __syncthreads();
        if (!half) { s1[j] = sv + tmp[j]; accg[j] = 0.f; }  // ws re-poisoned each call
    }
}

// ---- scatter 2: pS[x][col] += w*dinv[row], pU[x][row] += w*dinv[col] (2 atomics/edge) ----
__global__ __launch_bounds__(256) void k_scat2(const int4* __restrict__ col4,
                                               const int4* __restrict__ row4,
                                               const float4* __restrict__ w4,
                                               const float* __restrict__ dinv,
                                               float* __restrict__ pS,
                                               float* __restrict__ pU) {
    int e = blockIdx.x * 256 + threadIdx.x;
    if (e >= NQ4) return;
    const int x = xcc();
    float* S = pS + (size_t)x * NNP;
    float* U = pU + (size_t)x * NNP;
    int4  c = col4[e];
    int4  r = row4[e];
    float4 w = w4[e];
    // issue all gathers before the atomics (ILP over L2 latency)
    float dr0 = dinv[r.x], dr1 = dinv[r.y], dr2 = dinv[r.z], dr3 = dinv[r.w];
    float dc0 = dinv[c.x], dc1 = dinv[c.y], dc2 = dinv[c.z], dc3 = dinv[c.w];
    gadd(&S[c.x], w.x * dr0);
    gadd(&S[c.y], w.y * dr1);
    gadd(&S[c.z], w.z * dr2);
    gadd(&S[c.w], w.w * dr3);
    gadd(&U[r.x], w.x * dc0);
    gadd(&U[r.y], w.y * dc1);
    gadd(&U[r.z], w.z * dc2);
    gadd(&U[r.w], w.w * dc3);
}

// ---- reduce 2 + node-dot (c/wgt never hit HBM):
//  c = dinv*(S+dinv), wgt = dinv*(U+dinv);  accg[j] += sum_v wgt*relu(c*s1[j]+b1[j])
__global__ __launch_bounds__(256) void k_red2node(const float* __restrict__ pS,
                                                  const float* __restrict__ pU,
                                                  const float* __restrict__ dinv,
                                                  const float* __restrict__ s1,
                                                  const float* __restrict__ b1,
                                                  float* __restrict__ accg) {
    __shared__ float4 ldsC[256], ldsW[256];    // 1024 nodes per block
    __shared__ float red[D];
    const int t = threadIdx.x;
    const int v4 = blockIdx.x * 256 + t;       // grid covers NNP4 exactly

    float4 S = make_float4(0, 0, 0, 0), U = make_float4(0, 0, 0, 0);
    #pragma unroll
    for (int x = 0; x < NXCD; ++x) {
        float4 a = ((const float4*)(pS + (size_t)x * NNP))[v4];
        float4 u = ((const float4*)(pU + (size_t)x * NNP))[v4];
        S.x += a.x; S.y += a.y; S.z += a.z; S.w += a.w;
        U.x += u.x; U.y += u.y; U.z += u.z; U.w += u.w;
    }
    float4 dv = ((const float4*)dinv)[v4];
    float4 cc, ww;
    cc.x = dv.x * (S.x + dv.x); cc.y = dv.y * (S.y + dv.y);
    cc.z = dv.z * (S.z + dv.z); cc.w = dv.w * (S.w + dv.w);
    ww.x = dv.x * (U.x + dv.x); ww.y = dv.y * (U.y + dv.y);
    ww.z = dv.z * (U.z + dv.z); ww.w = dv.w * (U.w + dv.w);
    int v0 = v4 * 4;                           // mask padded fake nodes
    if (v0 + 0 >= NN) ww.x = 0.f;
    if (v0 + 1 >= NN) ww.y = 0.f;
    if (v0 + 2 >= NN) ww.z = 0.f;
    if (v0 + 3 >= NN) ww.w = 0.f;
    ldsC[t] = cc; ldsW[t] = ww;
    __syncthreads();

    // node-dot: 2 j-groups of 128 lanes; group g scans 128 float4 node-packs
    const int j = t & (D - 1), g = t >> 7;
    const float sj = s1[j], bj = b1[j];
    float acc = 0.f;
    #pragma unroll 8
    for (int k = 0; k < 128; ++k) {
        float4 c4 = ldsC[g * 128 + k];         // wave-uniform LDS broadcast
        float4 w4 = ldsW[g * 128 + k];
        acc += w4.x * fmaxf(fmaf(c4.x, sj, bj), 0.f);
        acc += w4.y * fmaxf(fmaf(c4.y, sj, bj), 0.f);
        acc += w4.z * fmaxf(fmaf(c4.z, sj, bj), 0.f);
        acc += w4.w * fmaxf(fmaf(c4.w, sj, bj), 0.f);
    }
    if (g) red[j] = acc;
    __syncthreads();
    if (!g) gadd(&accg[j], acc + red[j]);      // 128 atomics/block, 98 blocks
}

// ---- gemv: out[k] = (1/N) * sum_j accg[j]*W2[j][k] + b2[k] ----
__global__ __launch_bounds__(256) void k_gemv(const float* __restrict__ accg,
                                              const float* __restrict__ W2,
                                              const float* __restrict__ b2,
                                              float* __restrict__ out) {
    __shared__ float a[D], r2[D];
    int t = threadIdx.x, k = t & (D - 1), g = t >> 7;
    if (t < D) a[t] = accg[t];
    __syncthreads();
    float o = 0.f;
    int j0 = g * 64;
    #pragma unroll 16
    for (int j = j0; j < j0 + 64; ++j) o = fmaf(a[j], W2[j * D + k], o);
    if (g) r2[k] = o;
    __syncthreads();
    if (!g) out[k] = (o + r2[k]) * (1.0f / (float)NN) + b2[k];
}

extern "C" void kernel_launch(void* const* d_in, const int* in_sizes, int n_in,
                              void* d_out, int out_size, void* d_ws, size_t ws_size,
                              hipStream_t stream) {
    // inputs: 0=x (unused; ref overwrites with ones), 1=edge_index [2,E] int,
    //         2=edge_attr [E] f32, 3=W1, 4=b1, 5=W2, 6=b2 (all f32)
    const int* ei    = (const int*)d_in[1];
    const int4* row4 = (const int4*)ei;
    const int4* col4 = (const int4*)(ei + NE);
    const float4* w4 = (const float4*)d_in[2];
    const float* W1 = (const float*)d_in[3];
    const float* b1 = (const float*)d_in[4];
    const float* W2 = (const float*)d_in[5];
    const float* b2 = (const float*)d_in[6];
    float* out = (float*)d_out;

    float* ws   = (float*)d_ws;
    float* pDeg = ws;                          // [NXCD*NNP] degree partials
    float* pS   = pDeg + (size_t)NXCD * NNP;   // [NXCD*NNP]
    float* pU   = pS   + (size_t)NXCD * NNP;   // [NXCD*NNP]
    float* dinv = pU   + (size_t)NXCD * NNP;   // [NNP]
    float* s1   = dinv + NNP;                  // [D]
    float* accg = s1 + D;                      // [D]
    // total ~9.7 MB << ws_size

    hipMemsetAsync(ws, 0, (size_t)3 * NXCD * NNP * sizeof(float), stream);
    k_scat1   <<<SCATB, 256, 0, stream>>>(col4, w4, pDeg);
    k_red1    <<<REDB, 256, 0, stream>>>(pDeg, W1, dinv, s1, accg);
    k_scat2   <<<SCATB, 256, 0, stream>>>(col4, row4, w4, dinv, pS, pU);
    k_red2node<<<REDB, 256, 0, stream>>>(pS, pU, dinv, s1, b1, accg);
    k_gemv    <<<1, 256, 0, stream>>>(accg, W2, b2, out);
}

// Round 3
// 353.435 us; speedup vs baseline: 1.0026x; 1.0022x over previous
//
#include <hip/hip_runtime.h>

#define NN    100000
#define NE    1600000
#define NQ4   (NE / 4)            // 400000 int4/float4 quads
#define D     128
#define NXCD  8
#define NNP   100352              // 98*1024: >= NN, NNP/4 divisible by 256
#define NNP4  (NNP / 4)           // 25088 = 98*256
#define SCATB ((NQ4 + 255) / 256) // 1563 blocks, 1 quad per thread
#define REDB  (NNP4 / 256)        // 98 blocks, 1 float4 per thread

// Per-wave hardware XCD id (verified on MI355X via s_getreg, learn_hip m09).
// Selects a private partial array -> no cache line is atomically touched by
// two XCDs, which makes LOCAL-L2 atomic execution correct by construction.
__device__ __forceinline__ int xcc() {
    int x;
    asm volatile("s_getreg_b32 %0, hwreg(HW_REG_XCC_ID)" : "=s"(x));
    return x & (NXCD - 1);
}

// Local-L2 fp32 atomic add. HIP atomicAdd/unsafeAtomicAdd are AGENT scope ->
// on 8-XCD gfx950 they bypass L2 and execute memory-side (measured r1/r2:
// 32B write-through per atomic, 100 MB WRITE_SIZE, 164 us). Raw
// global_atomic_add_f32 with no sc1 bit executes in the issuing XCD's L2;
// per-XCD array privatization guarantees no cross-XCD same-line atomics, and
// the dispatch-end release writes L2 back for the next kernel.
__device__ __forceinline__ void gadd(float* p, float v) {
    asm volatile("global_atomic_add_f32 %0, %1, off" :: "v"(p), "v"(v) : "memory");
}

// ---- scatter 1: per-XCD degree partials pDeg[x][v] += w (1 atomic/edge) ----
__global__ __launch_bounds__(256) void k_scat1(const int4* __restrict__ col4,
                                               const float4* __restrict__ w4,
                                               float* __restrict__ pDeg) {
    int e = blockIdx.x * 256 + threadIdx.x;
    if (e >= NQ4) return;
    float* p = pDeg + (size_t)xcc() * NNP;
    int4  c = col4[e];
    float4 w = w4[e];
    gadd(&p[c.x], w.x);
    gadd(&p[c.y], w.y);
    gadd(&p[c.z], w.z);
    gadd(&p[c.w], w.w);
}

// ---- reduce 1: dinv = rsqrt(1 + sum_x pDeg[x][v]); block 0: s1 = colsum(W1), accg = 0 ----
__global__ __launch_bounds__(256) void k_red1(const float* __restrict__ pDeg,
                                              const float* __restrict__ W1,
                                              float* __restrict__ dinv,
                                              float* __restrict__ s1,
                                              float* __restrict__ accg) {
    const int t = threadIdx.x;
    const int v4 = blockIdx.x * 256 + t;       // grid covers NNP4 exactly
    float4 a = make_float4(1.f, 1.f, 1.f, 1.f); // self-loop weight
    #pragma unroll
    for (int x = 0; x < NXCD; ++x) {
        float4 p = ((const float4*)(pDeg + (size_t)x * NNP))[v4];
        a.x += p.x; a.y += p.y; a.z += p.z; a.w += p.w;
    }
    float4 r;
    r.x = rsqrtf(a.x); r.y = rsqrtf(a.y); r.z = rsqrtf(a.z); r.w = rsqrtf(a.w);
    ((float4*)dinv)[v4] = r;

    if (blockIdx.x == 0) {
        __shared__ float tmp[D];
        int j = t & (D - 1), half = t >> 7;    // 2 halves x 64 rows
        float sv = 0.f;
        #pragma unroll 16
        for (int rr = half * 64; rr < half * 64 + 64; ++rr) sv += W1[rr * D + j];
        if (half) tmp[j] = sv;
        __syncthreads();
        if (!half) { s1[j] = sv + tmp[j]; accg[j] = 0.f; }  // ws re-poisoned each call
    }
}

// ---- scatter 2: pS[x][col] += w*dinv[row], pU[x][row] += w*dinv[col] (2 atomics/edge) ----
__global__ __launch_bounds__(256) void k_scat2(const int4* __restrict__ col4,
                                               const int4* __restrict__ row4,
                                               const float4* __restrict__ w4,
                                               const float* __restrict__ dinv,
                                               float* __restrict__ pS,
                                               float* __restrict__ pU) {
    int e = blockIdx.x * 256 + threadIdx.x;
    if (e >= NQ4) return;
    const int x = xcc();
    float* S = pS + (size_t)x * NNP;
    float* U = pU + (size_t)x * NNP;
    int4  c = col4[e];
    int4  r = row4[e];
    float4 w = w4[e];
    // issue all gathers before the atomics (ILP over L2 latency)
    float dr0 = dinv[r.x], dr1 = dinv[r.y], dr2 = dinv[r.z], dr3 = dinv[r.w];
    float dc0 = dinv[c.x], dc1 = dinv[c.y], dc2 = dinv[c.z], dc3 = dinv[c.w];
    gadd(&S[c.x], w.x * dr0);
    gadd(&S[c.y], w.y * dr1);
    gadd(&S[c.z], w.z * dr2);
    gadd(&S[c.w], w.w * dr3);
    gadd(&U[r.x], w.x * dc0);
    gadd(&U[r.y], w.y * dc1);
    gadd(&U[r.z], w.z * dc2);
    gadd(&U[r.w], w.w * dc3);
}

// ---- reduce 2 + node-dot (c/wgt never hit HBM):
//  c = dinv*(S+dinv), wgt = dinv*(U+dinv);  accg[j] += sum_v wgt*relu(c*s1[j]+b1[j])
__global__ __launch_bounds__(256) void k_red2node(const float* __restrict__ pS,
                                                  const float* __restrict__ pU,
                                                  const float* __restrict__ dinv,
                                                  const float* __restrict__ s1,
                                                  const float* __restrict__ b1,
                                                  float* __restrict__ accg) {
    __shared__ float4 ldsC[256], ldsW[256];    // 1024 nodes per block
    __shared__ float red[D];
    const int t = threadIdx.x;
    const int v4 = blockIdx.x * 256 + t;       // grid covers NNP4 exactly

    float4 S = make_float4(0, 0, 0, 0), U = make_float4(0, 0, 0, 0);
    #pragma unroll
    for (int x = 0; x < NXCD; ++x) {
        float4 a = ((const float4*)(pS + (size_t)x * NNP))[v4];
        float4 u = ((const float4*)(pU + (size_t)x * NNP))[v4];
        S.x += a.x; S.y += a.y; S.z += a.z; S.w += a.w;
        U.x += u.x; U.y += u.y; U.z += u.z; U.w += u.w;
    }
    float4 dv = ((const float4*)dinv)[v4];
    float4 cc, ww;
    cc.x = dv.x * (S.x + dv.x); cc.y = dv.y * (S.y + dv.y);
    cc.z = dv.z * (S.z + dv.z); cc.w = dv.w * (S.w + dv.w);
    ww.x = dv.x * (U.x + dv.x); ww.y = dv.y * (U.y + dv.y);
    ww.z = dv.z * (U.z + dv.z); ww.w = dv.w * (U.w + dv.w);
    int v0 = v4 * 4;                           // mask padded fake nodes
    if (v0 + 0 >= NN) ww.x = 0.f;
    if (v0 + 1 >= NN) ww.y = 0.f;
    if (v0 + 2 >= NN) ww.z = 0.f;
    if (v0 + 3 >= NN) ww.w = 0.f;
    ldsC[t] = cc; ldsW[t] = ww;
    __syncthreads();

    // node-dot: 2 j-groups of 128 lanes; group g scans 128 float4 node-packs
    const int j = t & (D - 1), g = t >> 7;
    const float sj = s1[j], bj = b1[j];
    float acc = 0.f;
    #pragma unroll 8
    for (int k = 0; k < 128; ++k) {
        float4 c4 = ldsC[g * 128 + k];         // wave-uniform LDS broadcast
        float4 w4 = ldsW[g * 128 + k];
        acc += w4.x * fmaxf(fmaf(c4.x, sj, bj), 0.f);
        acc += w4.y * fmaxf(fmaf(c4.y, sj, bj), 0.f);
        acc += w4.z * fmaxf(fmaf(c4.z, sj, bj), 0.f);
        acc += w4.w * fmaxf(fmaf(c4.w, sj, bj), 0.f);
    }
    if (g) red[j] = acc;
    __syncthreads();
    // accg is accumulated from blocks on ALL XCDs -> must stay device-scope.
    if (!g) atomicAdd(&accg[j], acc + red[j]); // 128 atomics/block, 98 blocks
}

// ---- gemv: out[k] = (1/N) * sum_j accg[j]*W2[j][k] + b2[k] ----
__global__ __launch_bounds__(256) void k_gemv(const float* __restrict__ accg,
                                              const float* __restrict__ W2,
                                              const float* __restrict__ b2,
                                              float* __restrict__ out) {
    __shared__ float a[D], r2[D];
    int t = threadIdx.x, k = t & (D - 1), g = t >> 7;
    if (t < D) a[t] = accg[t];
    __syncthreads();
    float o = 0.f;
    int j0 = g * 64;
    #pragma unroll 16
    for (int j = j0; j < j0 + 64; ++j) o = fmaf(a[j], W2[j * D + k], o);
    if (g) r2[k] = o;
    __syncthreads();
    if (!g) out[k] = (o + r2[k]) * (1.0f / (float)NN) + b2[k];
}

extern "C" void kernel_launch(void* const* d_in, const int* in_sizes, int n_in,
                              void* d_out, int out_size, void* d_ws, size_t ws_size,
                              hipStream_t stream) {
    // inputs: 0=x (unused; ref overwrites with ones), 1=edge_index [2,E] int,
    //         2=edge_attr [E] f32, 3=W1, 4=b1, 5=W2, 6=b2 (all f32)
    const int* ei    = (const int*)d_in[1];
    const int4* row4 = (const int4*)ei;
    const int4* col4 = (const int4*)(ei + NE);
    const float4* w4 = (const float4*)d_in[2];
    const float* W1 = (const float*)d_in[3];
    const float* b1 = (const float*)d_in[4];
    const float* W2 = (const float*)d_in[5];
    const float* b2 = (const float*)d_in[6];
    float* out = (float*)d_out;

    float* ws   = (float*)d_ws;
    float* pDeg = ws;                          // [NXCD*NNP] degree partials
    float* pS   = pDeg + (size_t)NXCD * NNP;   // [NXCD*NNP]
    float* pU   = pS   + (size_t)NXCD * NNP;   // [NXCD*NNP]
    float* dinv = pU   + (size_t)NXCD * NNP;   // [NNP]
    float* s1   = dinv + NNP;                  // [D]
    float* accg = s1 + D;                      // [D]
    // total ~9.7 MB << ws_size

    hipMemsetAsync(ws, 0, (size_t)3 * NXCD * NNP * sizeof(float), stream);
    k_scat1   <<<SCATB, 256, 0, stream>>>(col4, w4, pDeg);
    k_red1    <<<REDB, 256, 0, stream>>>(pDeg, W1, dinv, s1, accg);
    k_scat2   <<<SCATB, 256, 0, stream>>>(col4, row4, w4, dinv, pS, pU);
    k_red2node<<<REDB, 256, 0, stream>>>(pS, pU, dinv, s1, b1, accg);
    k_gemv    <<<1, 256, 0, stream>>>(accg, W2, b2, out);
}

// Round 4
// 188.296 us; speedup vs baseline: 1.8819x; 1.8770x over previous
//
#include <hip/hip_runtime.h>

#define NN    100000
#define NE    1600000
#define NQ4   (NE / 4)            // 400000 quads
#define D     128
#define NBIN  8
#define BSZ   12512               // nodes/bin, 50 KB LDS; 8*12512=100096 >= NN
#define NNP   (NBIN * BSZ)        // 100096
#define NNP4  (NNP / 4)           // 25024
#define NBLK  1563                // hist/bucket blocks: 1563*256 >= NQ4
#define K     32                  // slices per bin
#define REDB  98                  // 98*256 >= NNP4 (guarded)

// ---- per-block histograms of col-bin and row-bin ----
__global__ __launch_bounds__(256) void k_hist(const int4* __restrict__ col4,
                                              const int4* __restrict__ row4,
                                              int* __restrict__ histC,
                                              int* __restrict__ histU) {
    __shared__ int hc[NBIN], hu[NBIN];
    int t = threadIdx.x;
    if (t < NBIN) { hc[t] = 0; hu[t] = 0; }
    __syncthreads();
    int e = blockIdx.x * 256 + t;
    if (e < NQ4) {
        int4 c = col4[e], r = row4[e];
        atomicAdd(&hc[c.x / BSZ], 1); atomicAdd(&hc[c.y / BSZ], 1);
        atomicAdd(&hc[c.z / BSZ], 1); atomicAdd(&hc[c.w / BSZ], 1);
        atomicAdd(&hu[r.x / BSZ], 1); atomicAdd(&hu[r.y / BSZ], 1);
        atomicAdd(&hu[r.z / BSZ], 1); atomicAdd(&hu[r.w / BSZ], 1);
    }
    __syncthreads();
    if (t < NBIN) {
        histC[t * NBLK + blockIdx.x] = hc[t];
        histU[t * NBLK + blockIdx.x] = hu[t];
    }
}

// ---- exclusive prefix over [bin][block] for C and U; also bin bases ----
__global__ __launch_bounds__(1024) void k_prefix(const int* __restrict__ histC,
                                                 const int* __restrict__ histU,
                                                 int* __restrict__ offC,
                                                 int* __restrict__ offU,
                                                 int* __restrict__ baseC,
                                                 int* __restrict__ baseU) {
    __shared__ int scan[1024];
    __shared__ int tot[16];
    __shared__ int baseS[9];
    const int t = threadIdx.x;
    const int g = t >> 7;                  // bin 0..7
    const int j = t & 127;                 // lane within bin group
    for (int pass = 0; pass < 2; ++pass) {
        const int* hist = pass ? histU : histC;
        int* off        = pass ? offU  : offC;
        int* gbase      = pass ? baseU : baseC;
        const int i0 = j * 13;             // 128*13 = 1664 >= NBLK
        int s = 0;
        #pragma unroll
        for (int q = 0; q < 13; ++q) {
            int idx = i0 + q;
            if (idx < NBLK) s += hist[g * NBLK + idx];
        }
        scan[t] = s;
        __syncthreads();
        #pragma unroll
        for (int st = 1; st < 128; st <<= 1) {   // inclusive scan per group
            int v = scan[t];
            int add = (j >= st) ? scan[t - st] : 0;
            __syncthreads();
            scan[t] = v + add;
            __syncthreads();
        }
        if (j == 127) tot[pass * 8 + g] = scan[t];
        __syncthreads();
        int excl = (j == 0) ? 0 : scan[t - 1];
        if (t == 0) {
            int b = 0;
            for (int q = 0; q < NBIN; ++q) { baseS[q] = b; b += tot[pass * 8 + q]; }
            baseS[NBIN] = b;
            for (int q = 0; q <= NBIN; ++q) gbase[q] = baseS[q];
        }
        __syncthreads();
        int run = baseS[g] + excl;
        #pragma unroll
        for (int q = 0; q < 13; ++q) {
            int idx = i0 + q;
            if (idx < NBLK) { off[g * NBLK + idx] = run; run += hist[g * NBLK + idx]; }
        }
        __syncthreads();
    }
}

// ---- bucketize: recC by col-bin (col_local | row<<14, w); recU by row-bin ----
__global__ __launch_bounds__(256) void k_bucket(const int4* __restrict__ col4,
                                                const int4* __restrict__ row4,
                                                const float4* __restrict__ w4,
                                                const int* __restrict__ offC,
                                                const int* __restrict__ offU,
                                                uint2* __restrict__ recC,
                                                uint2* __restrict__ recU) {
    __shared__ int oc[NBIN], ou[NBIN], cc[NBIN], cu[NBIN];
    int t = threadIdx.x;
    if (t < NBIN) {
        oc[t] = offC[t * NBLK + blockIdx.x]; cc[t] = 0;
        ou[t] = offU[t * NBLK + blockIdx.x]; cu[t] = 0;
    }
    __syncthreads();
    int e = blockIdx.x * 256 + t;
    if (e >= NQ4) return;
    int4 c = col4[e]; int4 r = row4[e]; float4 w = w4[e];
    #define PUT(COL, ROW, W)                                                    \
        {                                                                       \
            int bc = (COL) / BSZ;                                               \
            int rk = atomicAdd(&cc[bc], 1);                                     \
            recC[oc[bc] + rk] = make_uint2(                                     \
                (unsigned)(((COL) - bc * BSZ) | ((ROW) << 14)),                 \
                __float_as_uint(W));                                            \
            int br = (ROW) / BSZ;                                               \
            rk = atomicAdd(&cu[br], 1);                                         \
            recU[ou[br] + rk] = make_uint2(                                     \
                (unsigned)(((ROW) - br * BSZ) | ((COL) << 14)),                 \
                __float_as_uint(W));                                            \
        }
    PUT(c.x, r.x, w.x) PUT(c.y, r.y, w.y) PUT(c.z, r.z, w.z) PUT(c.w, r.w, w.w)
    #undef PUT
}

// ---- dense deg scatter: block (b,k) scans slice k of bucket b, all hits ----
__global__ __launch_bounds__(1024) void k_scatdeg(const uint2* __restrict__ recC,
                                                  const int* __restrict__ baseC,
                                                  float* __restrict__ pDegP) {
    __shared__ float bin[BSZ];
    int b = blockIdx.x >> 5, k = blockIdx.x & 31;
    float4* bin4 = (float4*)bin;
    for (int i = threadIdx.x; i < BSZ / 4; i += 1024) bin4[i] = make_float4(0, 0, 0, 0);
    __syncthreads();
    int s0 = baseC[b], n = baseC[b + 1] - s0;
    int lo = s0 + ((n * k) >> 5), hi = s0 + ((n * (k + 1)) >> 5);
    for (int i = lo + threadIdx.x; i < hi; i += 1024) {
        uint2 rc = recC[i];
        atomicAdd(&bin[rc.x & 0x3FFF], __uint_as_float(rc.y));
    }
    __syncthreads();
    float4* dst = (float4*)(pDegP + (size_t)k * NNP + b * BSZ);
    for (int i = threadIdx.x; i < BSZ / 4; i += 1024) dst[i] = bin4[i];
}

// ---- reduce 1: dinv = rsqrt(1 + sum_k pDegP); block 0: s1 = colsum(W1), accg = 0 ----
__global__ __launch_bounds__(256) void k_red1(const float* __restrict__ pDegP,
                                              const float* __restrict__ W1,
                                              float* __restrict__ dinv,
                                              float* __restrict__ s1,
                                              float* __restrict__ accg) {
    const int t = threadIdx.x;
    const int v4 = blockIdx.x * 256 + t;
    if (v4 < NNP4) {
        float4 a = make_float4(1.f, 1.f, 1.f, 1.f);   // self-loop weight
        #pragma unroll 8
        for (int k = 0; k < K; ++k) {
            float4 p = ((const float4*)(pDegP + (size_t)k * NNP))[v4];
            a.x += p.x; a.y += p.y; a.z += p.z; a.w += p.w;
        }
        float4 r;
        r.x = rsqrtf(a.x); r.y = rsqrtf(a.y); r.z = rsqrtf(a.z); r.w = rsqrtf(a.w);
        ((float4*)dinv)[v4] = r;
    }
    if (blockIdx.x == 0) {
        __shared__ float tmp[D];
        int j = t & (D - 1), half = t >> 7;
        float sv = 0.f;
        #pragma unroll 16
        for (int rr = half * 64; rr < half * 64 + 64; ++rr) sv += W1[rr * D + j];
        if (half) tmp[j] = sv;
        __syncthreads();
        if (!half) { s1[j] = sv + tmp[j]; accg[j] = 0.f; }  // ws re-poisoned each call
    }
}

// ---- dense S/U scatter: blocks 0-255 do S (recC), 256-511 do U (recU) ----
__global__ __launch_bounds__(1024) void k_scatSU(const uint2* __restrict__ recC,
                                                 const uint2* __restrict__ recU,
                                                 const int* __restrict__ baseC,
                                                 const int* __restrict__ baseU,
                                                 const float* __restrict__ dinv,
                                                 float* __restrict__ pSP,
                                                 float* __restrict__ pUP) {
    __shared__ float bin[BSZ];                 // 50 KB -> 2 blocks/CU, 32 waves
    int role = blockIdx.x >> 8;                // 0: S, 1: U
    int id = blockIdx.x & 255;
    int b = id >> 5, k = id & 31;
    float4* bin4 = (float4*)bin;
    for (int i = threadIdx.x; i < BSZ / 4; i += 1024) bin4[i] = make_float4(0, 0, 0, 0);
    __syncthreads();
    const uint2* rec = role ? recU : recC;
    const int* base  = role ? baseU : baseC;
    float* dstP      = role ? pUP  : pSP;
    int s0 = base[b], n = base[b + 1] - s0;
    int lo = s0 + ((n * k) >> 5), hi = s0 + ((n * (k + 1)) >> 5);
    for (int i = lo + threadIdx.x; i < hi; i += 1024) {
        uint2 rc = rec[i];
        float dv = dinv[rc.x >> 14];           // dinv[row] for S, dinv[col] for U
        atomicAdd(&bin[rc.x & 0x3FFF], __uint_as_float(rc.y) * dv);
    }
    __syncthreads();
    float4* dst = (float4*)(dstP + (size_t)k * NNP + b * BSZ);
    for (int i = threadIdx.x; i < BSZ / 4; i += 1024) dst[i] = bin4[i];
}

// ---- reduce 2 + node-dot: c = dinv*(S+dinv), wgt = dinv*(U+dinv);
//      accg[j] += sum_v wgt*relu(c*s1[j]+b1[j]) ----
__global__ __launch_bounds__(256) void k_red2node(const float* __restrict__ pSP,
                                                  const float* __restrict__ pUP,
                                                  const float* __restrict__ dinv,
                                                  const float* __restrict__ s1,
                                                  const float* __restrict__ b1,
                                                  float* __restrict__ accg) {
    __shared__ float4 ldsC[256], ldsW[256];    // 1024 nodes per block
    __shared__ float red[D];
    const int t = threadIdx.x;
    const int v4 = blockIdx.x * 256 + t;

    float4 cc = make_float4(0, 0, 0, 0), ww = make_float4(0, 0, 0, 0);
    if (v4 < NNP4) {
        float4 S = make_float4(0, 0, 0, 0), U = make_float4(0, 0, 0, 0);
        #pragma unroll 8
        for (int k = 0; k < K; ++k) {
            float4 a = ((const float4*)(pSP + (size_t)k * NNP))[v4];
            float4 u = ((const float4*)(pUP + (size_t)k * NNP))[v4];
            S.x += a.x; S.y += a.y; S.z += a.z; S.w += a.w;
            U.x += u.x; U.y += u.y; U.z += u.z; U.w += u.w;
        }
        float4 dv = ((const float4*)dinv)[v4];
        cc.x = dv.x * (S.x + dv.x); cc.y = dv.y * (S.y + dv.y);
        cc.z = dv.z * (S.z + dv.z); cc.w = dv.w * (S.w + dv.w);
        ww.x = dv.x * (U.x + dv.x); ww.y = dv.y * (U.y + dv.y);
        ww.z = dv.z * (U.z + dv.z); ww.w = dv.w * (U.w + dv.w);
        int v0 = v4 * 4;                       // mask padded fake nodes
        if (v0 + 0 >= NN) ww.x = 0.f;
        if (v0 + 1 >= NN) ww.y = 0.f;
        if (v0 + 2 >= NN) ww.z = 0.f;
        if (v0 + 3 >= NN) ww.w = 0.f;
    }
    ldsC[t] = cc; ldsW[t] = ww;
    __syncthreads();

    const int j = t & (D - 1), g = t >> 7;
    const float sj = s1[j], bj = b1[j];
    float acc = 0.f;
    #pragma unroll 8
    for (int k = 0; k < 128; ++k) {
        float4 c4 = ldsC[g * 128 + k];
        float4 w4 = ldsW[g * 128 + k];
        acc += w4.x * fmaxf(fmaf(c4.x, sj, bj), 0.f);
        acc += w4.y * fmaxf(fmaf(c4.y, sj, bj), 0.f);
        acc += w4.z * fmaxf(fmaf(c4.z, sj, bj), 0.f);
        acc += w4.w * fmaxf(fmaf(c4.w, sj, bj), 0.f);
    }
    if (g) red[j] = acc;
    __syncthreads();
    if (!g) atomicAdd(&accg[j], acc + red[j]); // 12.5K global atomics total: cheap
}

// ---- gemv: out[k] = (1/N) * sum_j accg[j]*W2[j][k] + b2[k] ----
__global__ __launch_bounds__(256) void k_gemv(const float* __restrict__ accg,
                                              const float* __restrict__ W2,
                                              const float* __restrict__ b2,
                                              float* __restrict__ out) {
    __shared__ float a[D], r2[D];
    int t = threadIdx.x, k = t & (D - 1), g = t >> 7;
    if (t < D) a[t] = accg[t];
    __syncthreads();
    float o = 0.f;
    int j0 = g * 64;
    #pragma unroll 16
    for (int j = j0; j < j0 + 64; ++j) o = fmaf(a[j], W2[j * D + k], o);
    if (g) r2[k] = o;
    __syncthreads();
    if (!g) out[k] = (o + r2[k]) * (1.0f / (float)NN) + b2[k];
}

extern "C" void kernel_launch(void* const* d_in, const int* in_sizes, int n_in,
                              void* d_out, int out_size, void* d_ws, size_t ws_size,
                              hipStream_t stream) {
    const int* ei    = (const int*)d_in[1];
    const int4* row4 = (const int4*)ei;
    const int4* col4 = (const int4*)(ei + NE);
    const float4* w4 = (const float4*)d_in[2];
    const float* W1 = (const float*)d_in[3];
    const float* b1 = (const float*)d_in[4];
    const float* W2 = (const float*)d_in[5];
    const float* b2 = (const float*)d_in[6];
    float* out = (float*)d_out;

    float* f    = (float*)d_ws;
    float* pDegP = f;                           // [K*NNP]
    float* pSP   = pDegP + (size_t)K * NNP;     // [K*NNP]
    float* pUP   = pSP   + (size_t)K * NNP;     // [K*NNP]
    float* dinv  = pUP   + (size_t)K * NNP;     // [NNP]
    float* s1    = dinv + NNP;                  // [D]
    float* accg  = s1 + D;                      // [D]
    int*  ints   = (int*)(accg + D);
    int*  histC  = ints;                        // [NBIN*NBLK]
    int*  histU  = histC + NBIN * NBLK;
    int*  offC   = histU + NBIN * NBLK;
    int*  offU   = offC + NBIN * NBLK;
    int*  baseC  = offU + NBIN * NBLK;          // [NBIN+1]
    int*  baseU  = baseC + (NBIN + 1);          // [NBIN+1]
    // 16-byte align the record arrays
    size_t off = ((size_t)((char*)(baseU + NBIN + 1) - (char*)d_ws) + 15) & ~(size_t)15;
    uint2* recC = (uint2*)((char*)d_ws + off);  // [NE] 12.8 MB
    uint2* recU = recC + NE;                    // [NE] 12.8 MB
    // total ~64 MB << ws_size; every array fully written before read -> no memset

    k_hist    <<<NBLK, 256, 0, stream>>>(col4, row4, histC, histU);
    k_prefix  <<<1, 1024, 0, stream>>>(histC, histU, offC, offU, baseC, baseU);
    k_bucket  <<<NBLK, 256, 0, stream>>>(col4, row4, w4, offC, offU, recC, recU);
    k_scatdeg <<<NBIN * K, 1024, 0, stream>>>(recC, baseC, pDegP);
    k_red1    <<<REDB, 256, 0, stream>>>(pDegP, W1, dinv, s1, accg);
    k_scatSU  <<<2 * NBIN * K, 1024, 0, stream>>>(recC, recU, baseC, baseU, dinv, pSP, pUP);
    k_red2node<<<REDB, 256, 0, stream>>>(pSP, pUP, dinv, s1, b1, accg);
    k_gemv    <<<1, 256, 0, stream>>>(accg, W2, b2, out);
}

// Round 5
// 173.459 us; speedup vs baseline: 2.0429x; 1.0855x over previous
//
#include <hip/hip_runtime.h>

#define NN    100000
#define NE    1600000
#define NQ4   (NE / 4)            // 400000 quads
#define D     128
#define P     32                 // edge slices
#define BINS  8                  // node bins
#define BSZ   12512              // nodes per bin (50 KB LDS); BINS*BSZ = 100096 >= NN
#define NNP   (BINS * BSZ)       // padded node stride (100096)
#define NNP4  (NNP / 4)          // 25024
#define SL4   (NE / 4 / P)       // quads per slice = 12500 (exact)
#define RB    391                // red2node blocks: 391*64 float4 == NNP4 exactly
#define MSGB  ((NQ4 + 255) / 256)

// XCD swizzle: blocks scanning the same edge slice s land on one XCD (blk%8 == s%8),
// so each slice's stream is HBM-fetched once and L2-served to the other 7 bin-blocks.
__device__ __forceinline__ void decode(int blk, int& b, int& s) {
    int x = blk & 7, y = blk >> 3;     // y in [0,32)
    s = (y & 3) * 8 + x;               // slice  [0,32)
    b = y >> 2;                        // bin    [0,8)
}

// ---- scatter 1: degree partials pA[s][v] = sum_{col=v, e in slice s} w[e] ----
__global__ __launch_bounds__(1024) void k_scat1(const int4* __restrict__ col4,
                                                const float4* __restrict__ w4,
                                                float* __restrict__ pA) {
    __shared__ float bin[BSZ];         // 50 KB -> 2 blocks/CU
    int b, s; decode(blockIdx.x, b, s);
    float4* bin4 = (float4*)bin;
    for (int i = threadIdx.x; i < BSZ / 4; i += 1024) bin4[i] = make_float4(0, 0, 0, 0);
    __syncthreads();
    const int lo = b * BSZ;
    const int e1 = (s + 1) * SL4;
    for (int e = s * SL4 + threadIdx.x; e < e1; e += 1024) {
        int4 k = col4[e];
        float4 v = w4[e];
        int r0 = k.x - lo, r1 = k.y - lo, r2 = k.z - lo, r3 = k.w - lo;
        if ((unsigned)r0 < (unsigned)BSZ) atomicAdd(&bin[r0], v.x);
        if ((unsigned)r1 < (unsigned)BSZ) atomicAdd(&bin[r1], v.y);
        if ((unsigned)r2 < (unsigned)BSZ) atomicAdd(&bin[r2], v.z);
        if ((unsigned)r3 < (unsigned)BSZ) atomicAdd(&bin[r3], v.w);
    }
    __syncthreads();
    float4* dst = (float4*)(pA + (size_t)s * NNP + lo);
    for (int i = threadIdx.x; i < BSZ / 4; i += 1024) dst[i] = bin4[i];
}

// ---- reduce 1: dinv = rsqrt(1 + sum_s pA[s][v]); block 0: s1 = colsum(W1), accg = 0 ----
__global__ __launch_bounds__(256) void k_red1(const float* __restrict__ pA,
                                              const float* __restrict__ W1,
                                              float* __restrict__ dinv,
                                              float* __restrict__ s1,
                                              float* __restrict__ accg) {
    int v4 = blockIdx.x * 256 + threadIdx.x;
    if (v4 < NNP4) {
        float4 a = make_float4(1.f, 1.f, 1.f, 1.f);   // self-loop weight
        #pragma unroll 8
        for (int ss = 0; ss < P; ++ss) {
            float4 p = ((const float4*)(pA + (size_t)ss * NNP))[v4];
            a.x += p.x; a.y += p.y; a.z += p.z; a.w += p.w;
        }
        float4 r;
        r.x = rsqrtf(a.x); r.y = rsqrtf(a.y); r.z = rsqrtf(a.z); r.w = rsqrtf(a.w);
        ((float4*)dinv)[v4] = r;
    }
    if (blockIdx.x == 0 && threadIdx.x < D) {
        int j = threadIdx.x;
        float sv = 0.f;
        for (int r = 0; r < D; ++r) sv += W1[r * D + j];
        s1[j] = sv;
        accg[j] = 0.f;                 // ws is re-poisoned before every call
    }
}

// ---- msg: dense per-edge precompute, gathers done ONCE (not once per bin replay):
//      m[e] = w*dinv[row]  (summed at col -> S),  u[e] = w*dinv[col]  (summed at row -> U)
__global__ __launch_bounds__(256) void k_msg(const int4* __restrict__ row4,
                                             const int4* __restrict__ col4,
                                             const float4* __restrict__ w4,
                                             const float* __restrict__ dinv,
                                             float4* __restrict__ m4,
                                             float4* __restrict__ u4) {
    int e = blockIdx.x * 256 + threadIdx.x;
    if (e >= NQ4) return;
    int4 kr = row4[e];
    int4 kc = col4[e];
    float4 w = w4[e];
    float dr0 = dinv[kr.x], dr1 = dinv[kr.y], dr2 = dinv[kr.z], dr3 = dinv[kr.w];
    float dc0 = dinv[kc.x], dc1 = dinv[kc.y], dc2 = dinv[kc.z], dc3 = dinv[kc.w];
    m4[e] = make_float4(w.x * dr0, w.y * dr1, w.z * dr2, w.w * dr3);
    u4[e] = make_float4(w.x * dc0, w.y * dc1, w.z * dc2, w.w * dc3);
}

// ---- scatter 2 (fused, gather-free): S[v]=sum_{col=v} m[e], U[v]=sum_{row=v} u[e] ----
__global__ __launch_bounds__(1024) void k_scat2(const int4* __restrict__ col4,
                                                const int4* __restrict__ row4,
                                                const float4* __restrict__ m4,
                                                const float4* __restrict__ u4,
                                                float* __restrict__ pS,
                                                float* __restrict__ pU) {
    __shared__ float binS[BSZ];
    __shared__ float binU[BSZ];        // 100 KB -> 1 block/CU (16 waves)
    int b, s; decode(blockIdx.x, b, s);
    float4* bS4 = (float4*)binS;
    float4* bU4 = (float4*)binU;
    for (int i = threadIdx.x; i < BSZ / 4; i += 1024) {
        bS4[i] = make_float4(0, 0, 0, 0);
        bU4[i] = make_float4(0, 0, 0, 0);
    }
    __syncthreads();
    const int lo = b * BSZ;
    const int e1 = (s + 1) * SL4;
    for (int e = s * SL4 + threadIdx.x; e < e1; e += 1024) {
        int4 kc = col4[e];
        int4 kr = row4[e];
        float4 m = m4[e];
        float4 u = u4[e];
        int c0 = kc.x - lo, c1 = kc.y - lo, c2 = kc.z - lo, c3 = kc.w - lo;
        int r0 = kr.x - lo, r1 = kr.y - lo, r2 = kr.z - lo, r3 = kr.w - lo;
        if ((unsigned)c0 < (unsigned)BSZ) atomicAdd(&binS[c0], m.x);
        if ((unsigned)c1 < (unsigned)BSZ) atomicAdd(&binS[c1], m.y);
        if ((unsigned)c2 < (unsigned)BSZ) atomicAdd(&binS[c2], m.z);
        if ((unsigned)c3 < (unsigned)BSZ) atomicAdd(&binS[c3], m.w);
        if ((unsigned)r0 < (unsigned)BSZ) atomicAdd(&binU[r0], u.x);
        if ((unsigned)r1 < (unsigned)BSZ) atomicAdd(&binU[r1], u.y);
        if ((unsigned)r2 < (unsigned)BSZ) atomicAdd(&binU[r2], u.z);
        if ((unsigned)r3 < (unsigned)BSZ) atomicAdd(&binU[r3], u.w);
    }
    __syncthreads();
    float4* dS = (float4*)(pS + (size_t)s * NNP + lo);
    float4* dU = (float4*)(pU + (size_t)s * NNP + lo);
    for (int i = threadIdx.x; i < BSZ / 4; i += 1024) { dS[i] = bS4[i]; dU[i] = bU4[i]; }
}

// ---- reduce 2 + node-dot (c/wgt never hit HBM):
//  c = dinv*(S+dinv), wgt = dinv*(U+dinv);  accg[j] += sum_v wgt*relu(c*s1[j]+b1[j])
__global__ __launch_bounds__(256) void k_red2node(const float* __restrict__ pS,
                                                  const float* __restrict__ pU,
                                                  const float* __restrict__ dinv,
                                                  const float* __restrict__ s1,
                                                  const float* __restrict__ b1,
                                                  float* __restrict__ accg) {
    __shared__ float4 sS[256], sU[256];       // 4-way slice-split partials
    __shared__ float4 ldsC[64], ldsW[64];     // 256 nodes per block
    __shared__ float red[D];
    const int t = threadIdx.x;
    const int q = t & 63;                     // float4 index within block chunk
    const int grp = t >> 6;                   // 0..3: slice sub-range
    const int v4 = blockIdx.x * 64 + q;       // 391*64 == NNP4 exactly

    // phase A: all 256 threads reduce 8 slices each of S and U
    float4 S = make_float4(0, 0, 0, 0), U = make_float4(0, 0, 0, 0);
    #pragma unroll
    for (int k = 0; k < P / 4; ++k) {
        int ss = grp * (P / 4) + k;
        float4 a = ((const float4*)(pS + (size_t)ss * NNP))[v4];
        float4 u = ((const float4*)(pU + (size_t)ss * NNP))[v4];
        S.x += a.x; S.y += a.y; S.z += a.z; S.w += a.w;
        U.x += u.x; U.y += u.y; U.z += u.z; U.w += u.w;
    }
    sS[t] = S; sU[t] = U;
    __syncthreads();
    if (t < 64) {
        float4 S0 = sS[t], S1 = sS[64 + t], S2 = sS[128 + t], S3 = sS[192 + t];
        float4 U0 = sU[t], U1 = sU[64 + t], U2 = sU[128 + t], U3 = sU[192 + t];
        float4 Sa, Ua;
        Sa.x = S0.x + S1.x + S2.x + S3.x; Sa.y = S0.y + S1.y + S2.y + S3.y;
        Sa.z = S0.z + S1.z + S2.z + S3.z; Sa.w = S0.w + S1.w + S2.w + S3.w;
        Ua.x = U0.x + U1.x + U2.x + U3.x; Ua.y = U0.y + U1.y + U2.y + U3.y;
        Ua.z = U0.z + U1.z + U2.z + U3.z; Ua.w = U0.w + U1.w + U2.w + U3.w;
        float4 dv = ((const float4*)dinv)[v4];
        float4 cc, ww;
        cc.x = dv.x * (Sa.x + dv.x); cc.y = dv.y * (Sa.y + dv.y);
        cc.z = dv.z * (Sa.z + dv.z); cc.w = dv.w * (Sa.w + dv.w);
        ww.x = dv.x * (Ua.x + dv.x); ww.y = dv.y * (Ua.y + dv.y);
        ww.z = dv.z * (Ua.z + dv.z); ww.w = dv.w * (Ua.w + dv.w);
        int v0 = v4 * 4;                      // mask padded fake nodes (v >= NN)
        if (v0 + 0 >= NN) ww.x = 0.f;
        if (v0 + 1 >= NN) ww.y = 0.f;
        if (v0 + 2 >= NN) ww.z = 0.f;
        if (v0 + 3 >= NN) ww.w = 0.f;
        ldsC[t] = cc; ldsW[t] = ww;
    }
    __syncthreads();

    // phase B: node-dot. 2 j-groups of 128 lanes; group g scans 32 float4 node-packs.
    const int j = t & (D - 1), g = t >> 7;
    const float sj = s1[j], bj = b1[j];
    float acc = 0.f;
    #pragma unroll
    for (int k = 0; k < 32; ++k) {
        float4 c4 = ldsC[g * 32 + k];         // wave-uniform LDS broadcast
        float4 w4 = ldsW[g * 32 + k];
        acc += w4.x * fmaxf(fmaf(c4.x, sj, bj), 0.f);
        acc += w4.y * fmaxf(fmaf(c4.y, sj, bj), 0.f);
        acc += w4.z * fmaxf(fmaf(c4.z, sj, bj), 0.f);
        acc += w4.w * fmaxf(fmaf(c4.w, sj, bj), 0.f);
    }
    if (g) red[j] = acc;
    __syncthreads();
    if (!g) atomicAdd(&accg[j], acc + red[j]);   // 128 atomics/block, 391 blocks
}

// ---- gemv: out[k] = (1/N) * sum_j accg[j]*W2[j][k] + b2[k] ----
__global__ __launch_bounds__(256) void k_gemv(const float* __restrict__ accg,
                                              const float* __restrict__ W2,
                                              const float* __restrict__ b2,
                                              float* __restrict__ out) {
    __shared__ float a[D], r2[D];
    int t = threadIdx.x, k = t & (D - 1), g = t >> 7;
    if (t < D) a[t] = accg[t];
    __syncthreads();
    float o = 0.f;
    int j0 = g * 64;
    #pragma unroll 16
    for (int j = j0; j < j0 + 64; ++j) o = fmaf(a[j], W2[j * D + k], o);
    if (g) r2[k] = o;
    __syncthreads();
    if (!g) out[k] = (o + r2[k]) * (1.0f / (float)NN) + b2[k];
}

extern "C" void kernel_launch(void* const* d_in, const int* in_sizes, int n_in,
                              void* d_out, int out_size, void* d_ws, size_t ws_size,
                              hipStream_t stream) {
    // inputs: 0=x (unused; ref overwrites with ones), 1=edge_index [2,E] int,
    //         2=edge_attr [E] f32, 3=W1, 4=b1, 5=W2, 6=b2 (all f32)
    const int* ei    = (const int*)d_in[1];
    const int4* row4 = (const int4*)ei;
    const int4* col4 = (const int4*)(ei + NE);
    const float4* w4 = (const float4*)d_in[2];
    const float* W1 = (const float*)d_in[3];
    const float* b1 = (const float*)d_in[4];
    const float* W2 = (const float*)d_in[5];
    const float* b2 = (const float*)d_in[6];
    float* out = (float*)d_out;

    float* ws   = (float*)d_ws;
    float* pA   = ws;                        // [P*NNP] deg partials, then S partials
    float* pB   = pA + (size_t)P * NNP;      // [P*NNP] U partials
    float* dinv = pB + (size_t)P * NNP;      // [NNP]
    float* s1   = dinv + NNP;                // [D]
    float* accg = s1 + D;                    // [D]
    float4* m4  = (float4*)(accg + D);       // [NQ4] 6.4 MB  w*dinv[row]
    float4* u4  = m4 + NQ4;                  // [NQ4] 6.4 MB  w*dinv[col]
    // total ~39 MB << ws_size; every array fully written before read -> no memset

    k_scat1   <<<BINS * P, 1024, 0, stream>>>(col4, w4, pA);
    k_red1    <<<(NNP4 + 255) / 256, 256, 0, stream>>>(pA, W1, dinv, s1, accg);
    k_msg     <<<MSGB, 256, 0, stream>>>(row4, col4, w4, dinv, m4, u4);
    k_scat2   <<<BINS * P, 1024, 0, stream>>>(col4, row4, m4, u4, pA, pB);
    k_red2node<<<RB, 256, 0, stream>>>(pA, pB, dinv, s1, b1, accg);
    k_gemv    <<<1, 256, 0, stream>>>(accg, W2, b2, out);
}

// Round 6
// 161.280 us; speedup vs baseline: 2.1972x; 1.0755x over previous
//
#include <hip/hip_runtime.h>

#define NN    100000
#define NE    1600000
#define D     128
#define P     32                 // edge slices
#define SL4   (NE / 4 / P)       // quads per slice = 12500 (exact)
#define HL4   (SL4 / 2)          // quads per half-slice = 6250
#define NC    64                 // half-slice chunks (scat1 partial dim)
#define NPAIR 4                  // bin-pairs
#define BSZ2  25024              // nodes per bin-pair (100 KB LDS)
#define NNP   (NPAIR * BSZ2)     // padded node stride (100096)
#define NNP4  (NNP / 4)          // 25024
#define RB    391                // red2node blocks: 391*64 float4 == NNP4 exactly

// XCD swizzle invariant: all blocks scanning the same edge chunk land on one
// XCD (blk%8 == chunk%8), so each chunk stream is HBM-fetched once and
// L2-served to the other pair/role blocks.

// ---- scatter 1: degree partials. block = (pair p, half-chunk c).
//      pA[c][p-window][v] = sum_{col=v, e in chunk c} w[e] ----
__global__ __launch_bounds__(1024) void k_scat1(const int4* __restrict__ col4,
                                                const float4* __restrict__ w4,
                                                float* __restrict__ pA) {
    __shared__ float bin[BSZ2];        // 100 KB -> 1 block/CU (16 waves)
    const int c = blockIdx.x & 63;     // half-chunk [0,64); blk%8 == c%8
    const int p = blockIdx.x >> 6;     // pair [0,4)
    float4* bin4 = (float4*)bin;
    for (int i = threadIdx.x; i < BSZ2 / 4; i += 1024) bin4[i] = make_float4(0, 0, 0, 0);
    __syncthreads();
    const int lo = p * BSZ2;
    const int e1 = (c + 1) * HL4;
    for (int e = c * HL4 + threadIdx.x; e < e1; e += 1024) {
        int4 k = col4[e];
        float4 v = w4[e];
        int r0 = k.x - lo, r1 = k.y - lo, r2 = k.z - lo, r3 = k.w - lo;
        if ((unsigned)r0 < (unsigned)BSZ2) atomicAdd(&bin[r0], v.x);
        if ((unsigned)r1 < (unsigned)BSZ2) atomicAdd(&bin[r1], v.y);
        if ((unsigned)r2 < (unsigned)BSZ2) atomicAdd(&bin[r2], v.z);
        if ((unsigned)r3 < (unsigned)BSZ2) atomicAdd(&bin[r3], v.w);
    }
    __syncthreads();
    float4* dst = (float4*)(pA + (size_t)c * NNP + lo);
    for (int i = threadIdx.x; i < BSZ2 / 4; i += 1024) dst[i] = bin4[i];
}

// ---- reduce 1: dinv = rsqrt(1 + sum_c pA[c][v]); block 0: s1 = colsum(W1), accg = 0 ----
__global__ __launch_bounds__(256) void k_red1(const float* __restrict__ pA,
                                              const float* __restrict__ W1,
                                              float* __restrict__ dinv,
                                              float* __restrict__ s1,
                                              float* __restrict__ accg) {
    int v4 = blockIdx.x * 256 + threadIdx.x;
    if (v4 < NNP4) {
        float4 a = make_float4(1.f, 1.f, 1.f, 1.f);   // self-loop weight
        #pragma unroll 8
        for (int cc = 0; cc < NC; ++cc) {
            float4 p = ((const float4*)(pA + (size_t)cc * NNP))[v4];
            a.x += p.x; a.y += p.y; a.z += p.z; a.w += p.w;
        }
        float4 r;
        r.x = rsqrtf(a.x); r.y = rsqrtf(a.y); r.z = rsqrtf(a.z); r.w = rsqrtf(a.w);
        ((float4*)dinv)[v4] = r;
    }
    if (blockIdx.x == 0 && threadIdx.x < D) {
        int j = threadIdx.x;
        float sv = 0.f;
        for (int r = 0; r < D; ++r) sv += W1[r * D + j];
        s1[j] = sv;
        accg[j] = 0.f;                 // ws is re-poisoned before every call
    }
}

// ---- scatter 2: block = (role, pair p, slice s), full slice per block.
//  role 0: pS[s][p-win][v] = sum_{col=v} w*dinv[row]
//  role 1: pU[s][p-win][v] = sum_{row=v} w*dinv[col]
//  dinv gather is PREDICATED under the bin test -> 8x fewer gather requests. ----
__global__ __launch_bounds__(1024) void k_scat2(const int4* __restrict__ col4,
                                                const int4* __restrict__ row4,
                                                const float4* __restrict__ w4,
                                                const float* __restrict__ dinv,
                                                float* __restrict__ pS,
                                                float* __restrict__ pU) {
    __shared__ float bin[BSZ2];        // 100 KB -> 1 block/CU (16 waves)
    const int role = blockIdx.x >> 7;  // 0: S, 1: U
    const int rem  = blockIdx.x & 127;
    const int p = rem >> 5;            // pair  [0,4)
    const int s = rem & 31;            // slice [0,32); blk%8 == s%8
    float4* bin4 = (float4*)bin;
    for (int i = threadIdx.x; i < BSZ2 / 4; i += 1024) bin4[i] = make_float4(0, 0, 0, 0);
    __syncthreads();
    const int4* idx4 = role ? row4 : col4;   // scatter index stream
    const int4* oth4 = role ? col4 : row4;   // gather index stream
    const int lo = p * BSZ2;
    const int e1 = (s + 1) * SL4;
    for (int e = s * SL4 + threadIdx.x; e < e1; e += 1024) {
        int4 a = idx4[e];
        int4 o = oth4[e];
        float4 w = w4[e];
        int i0 = a.x - lo, i1 = a.y - lo, i2 = a.z - lo, i3 = a.w - lo;
        if ((unsigned)i0 < (unsigned)BSZ2) atomicAdd(&bin[i0], w.x * dinv[o.x]);
        if ((unsigned)i1 < (unsigned)BSZ2) atomicAdd(&bin[i1], w.y * dinv[o.y]);
        if ((unsigned)i2 < (unsigned)BSZ2) atomicAdd(&bin[i2], w.z * dinv[o.z]);
        if ((unsigned)i3 < (unsigned)BSZ2) atomicAdd(&bin[i3], w.w * dinv[o.w]);
    }
    __syncthreads();
    float* dstP = role ? pU : pS;
    float4* dst = (float4*)(dstP + (size_t)s * NNP + lo);
    for (int i = threadIdx.x; i < BSZ2 / 4; i += 1024) dst[i] = bin4[i];
}

// ---- reduce 2 + node-dot (c/wgt never hit HBM):
//  c = dinv*(S+dinv), wgt = dinv*(U+dinv);  accg[j] += sum_v wgt*relu(c*s1[j]+b1[j])
__global__ __launch_bounds__(256) void k_red2node(const float* __restrict__ pS,
                                                  const float* __restrict__ pU,
                                                  const float* __restrict__ dinv,
                                                  const float* __restrict__ s1,
                                                  const float* __restrict__ b1,
                                                  float* __restrict__ accg) {
    __shared__ float4 sS[256], sU[256];       // 4-way slice-split partials
    __shared__ float4 ldsC[64], ldsW[64];     // 256 nodes per block
    __shared__ float red[D];
    const int t = threadIdx.x;
    const int q = t & 63;                     // float4 index within block chunk
    const int grp = t >> 6;                   // 0..3: slice sub-range
    const int v4 = blockIdx.x * 64 + q;       // 391*64 == NNP4 exactly

    // phase A: all 256 threads reduce 8 slices each of S and U
    float4 S = make_float4(0, 0, 0, 0), U = make_float4(0, 0, 0, 0);
    #pragma unroll
    for (int k = 0; k < P / 4; ++k) {
        int ss = grp * (P / 4) + k;
        float4 a = ((const float4*)(pS + (size_t)ss * NNP))[v4];
        float4 u = ((const float4*)(pU + (size_t)ss * NNP))[v4];
        S.x += a.x; S.y += a.y; S.z += a.z; S.w += a.w;
        U.x += u.x; U.y += u.y; U.z += u.z; U.w += u.w;
    }
    sS[t] = S; sU[t] = U;
    __syncthreads();
    if (t < 64) {
        float4 S0 = sS[t], S1 = sS[64 + t], S2 = sS[128 + t], S3 = sS[192 + t];
        float4 U0 = sU[t], U1 = sU[64 + t], U2 = sU[128 + t], U3 = sU[192 + t];
        float4 Sa, Ua;
        Sa.x = S0.x + S1.x + S2.x + S3.x; Sa.y = S0.y + S1.y + S2.y + S3.y;
        Sa.z = S0.z + S1.z + S2.z + S3.z; Sa.w = S0.w + S1.w + S2.w + S3.w;
        Ua.x = U0.x + U1.x + U2.x + U3.x; Ua.y = U0.y + U1.y + U2.y + U3.y;
        Ua.z = U0.z + U1.z + U2.z + U3.z; Ua.w = U0.w + U1.w + U2.w + U3.w;
        float4 dv = ((const float4*)dinv)[v4];
        float4 cc, ww;
        cc.x = dv.x * (Sa.x + dv.x); cc.y = dv.y * (Sa.y + dv.y);
        cc.z = dv.z * (Sa.z + dv.z); cc.w = dv.w * (Sa.w + dv.w);
        ww.x = dv.x * (Ua.x + dv.x); ww.y = dv.y * (Ua.y + dv.y);
        ww.z = dv.z * (Ua.z + dv.z); ww.w = dv.w * (Ua.w + dv.w);
        int v0 = v4 * 4;                      // mask padded fake nodes (v >= NN)
        if (v0 + 0 >= NN) ww.x = 0.f;
        if (v0 + 1 >= NN) ww.y = 0.f;
        if (v0 + 2 >= NN) ww.z = 0.f;
        if (v0 + 3 >= NN) ww.w = 0.f;
        ldsC[t] = cc; ldsW[t] = ww;
    }
    __syncthreads();

    // phase B: node-dot. 2 j-groups of 128 lanes; group g scans 32 float4 node-packs.
    const int j = t & (D - 1), g = t >> 7;
    const float sj = s1[j], bj = b1[j];
    float acc = 0.f;
    #pragma unroll
    for (int k = 0; k < 32; ++k) {
        float4 c4 = ldsC[g * 32 + k];         // wave-uniform LDS broadcast
        float4 w4 = ldsW[g * 32 + k];
        acc += w4.x * fmaxf(fmaf(c4.x, sj, bj), 0.f);
        acc += w4.y * fmaxf(fmaf(c4.y, sj, bj), 0.f);
        acc += w4.z * fmaxf(fmaf(c4.z, sj, bj), 0.f);
        acc += w4.w * fmaxf(fmaf(c4.w, sj, bj), 0.f);
    }
    if (g) red[j] = acc;
    __syncthreads();
    if (!g) atomicAdd(&accg[j], acc + red[j]);   // 128 atomics/block, 391 blocks
}

// ---- gemv: out[k] = (1/N) * sum_j accg[j]*W2[j][k] + b2[k] ----
__global__ __launch_bounds__(256) void k_gemv(const float* __restrict__ accg,
                                              const float* __restrict__ W2,
                                              const float* __restrict__ b2,
                                              float* __restrict__ out) {
    __shared__ float a[D], r2[D];
    int t = threadIdx.x, k = t & (D - 1), g = t >> 7;
    if (t < D) a[t] = accg[t];
    __syncthreads();
    float o = 0.f;
    int j0 = g * 64;
    #pragma unroll 16
    for (int j = j0; j < j0 + 64; ++j) o = fmaf(a[j], W2[j * D + k], o);
    if (g) r2[k] = o;
    __syncthreads();
    if (!g) out[k] = (o + r2[k]) * (1.0f / (float)NN) + b2[k];
}

extern "C" void kernel_launch(void* const* d_in, const int* in_sizes, int n_in,
                              void* d_out, int out_size, void* d_ws, size_t ws_size,
                              hipStream_t stream) {
    // inputs: 0=x (unused; ref overwrites with ones), 1=edge_index [2,E] int,
    //         2=edge_attr [E] f32, 3=W1, 4=b1, 5=W2, 6=b2 (all f32)
    const int* ei    = (const int*)d_in[1];
    const int4* row4 = (const int4*)ei;
    const int4* col4 = (const int4*)(ei + NE);
    const float4* w4 = (const float4*)d_in[2];
    const float* W1 = (const float*)d_in[3];
    const float* b1 = (const float*)d_in[4];
    const float* W2 = (const float*)d_in[5];
    const float* b2 = (const float*)d_in[6];
    float* out = (float*)d_out;

    float* ws   = (float*)d_ws;
    float* pA   = ws;                        // [NC*NNP] deg partials (25.6 MB)
    float* pS   = pA + (size_t)NC * NNP;     // [P*NNP]  S partials (12.8 MB)
    float* pU   = pS + (size_t)P * NNP;      // [P*NNP]  U partials (12.8 MB)
    float* dinv = pU + (size_t)P * NNP;      // [NNP]
    float* s1   = dinv + NNP;                // [D]
    float* accg = s1 + D;                    // [D]
    // total ~52 MB << ws_size; every array fully written before read -> no memset

    k_scat1   <<<NPAIR * NC, 1024, 0, stream>>>(col4, w4, pA);          // 256 blocks
    k_red1    <<<(NNP4 + 255) / 256, 256, 0, stream>>>(pA, W1, dinv, s1, accg);
    k_scat2   <<<2 * NPAIR * P, 1024, 0, stream>>>(col4, row4, w4, dinv, pS, pU); // 256
    k_red2node<<<RB, 256, 0, stream>>>(pS, pU, dinv, s1, b1, accg);
    k_gemv    <<<1, 256, 0, stream>>>(accg, W2, b2, out);
}